// Round 6
// baseline (161.485 us; speedup 1.0000x reference)
//
#include <hip/hip_runtime.h>

// EfficientAdditiveAttention  B=8, L=512, D=128
//
// combined(q,k) = sum_d w_all[d]*tanh(zq_d + zk_d)  -> softmax_k -> @V
// tanh = 1 - 2/(1+e^{2(zq+zk)});  e^{2(zq+zk)} = Eq*Ek with Eq,Ek PRECOMPUTED
// by the projection kernel. Softmax-invariant constants dropped. With
// w^ = -2*log2e*w_all:  p(k) = exp2( sum_d w^_d / (1+Eq_d*Ek_d) ).
// Hot loop per d-pair per q: e_j = fma(Eq,Ek,1) (x2); N = fma(w0,e1,w1*e0);
// s = fma(N, rcp(e0*e1), s)  ->  6 VALU + 1 rcp per 2 elements, Eq/w^ via
// s_load (scalar pipe), Ek via per-lane LDS row.
//
// v6: 1024 blocks x 512 thr; block = 32 q (8 waves x 4 q) x ONE 64-k tile
// (k-split 8). LDS = Ek tile only (64x132, 33.8 KB) -> 4 blocks/CU. P handed
// to pass B via v_readlane (no LDS). V read from global (L1/L2-shared).
// Partials -> f32 atomics; normalize kernel divides by psum.

#define BB 8
#define LL 512
#define DD 128
#define NROW (BB*LL)            // 4096 rows
#define MATN (NROW*DD)          // 524288 elements per matrix

static constexpr float C1 = 2.8853900817779268f;    // 2*log2(e)
static constexpr float LOG2E = 1.4426950408889634f;
static constexpr float INV_SCALE = 0.08838834764831845f; // 1/sqrt(128)

__device__ __forceinline__ float fast_exp2(float x) { return __builtin_amdgcn_exp2f(x); }
__device__ __forceinline__ float fast_rcp(float x)  { return __builtin_amdgcn_rcpf(x); }

// ---------------------------------------------------------------------------
// Projection: z = X @ W.T + b; outputs Eq=exp2(C1*z) (m=0), Ek=exp2(C1*z)
// (m=1), V=z (m=2). 32-row x 128-col tiles, 384 blocks x 256 threads.
// ---------------------------------------------------------------------------
__global__ __launch_bounds__(256) void proj_kernel(
    const float* __restrict__ query, const float* __restrict__ key,
    const float* __restrict__ value,
    const float* __restrict__ Wq, const float* __restrict__ bq,
    const float* __restrict__ Wk, const float* __restrict__ bk,
    const float* __restrict__ Wv, const float* __restrict__ bv,
    const float* __restrict__ wd, const float* __restrict__ wsg,
    const float* __restrict__ wtt, float* __restrict__ ws)
{
    __shared__ __align__(16) float Wl[128 * 66];   // 33792 B
    __shared__ __align__(16) float Xl[32 * 66];    //  8448 B

    const int bx = blockIdx.x;
    const int m  = bx >> 7;              // 0:Q 1:K 2:V  (128 row-tiles each)
    const int r0 = (bx & 127) * 32;
    const float* X    = (m == 0) ? query : (m == 1) ? key : value;
    const float* W    = (m == 0) ? Wq    : (m == 1) ? Wk  : Wv;
    const float* bias = (m == 0) ? bq    : (m == 1) ? bk  : bv;
    const int t = threadIdx.x;

    // w^ = -2*log2e*(1/sqrt(D) + wd + wsg + wtt)  -> ws tail (block 0)
    if (bx == 0 && t < 128) {
        ws[(size_t)3 * MATN + t] =
            -2.0f * LOG2E * (INV_SCALE + wd[t] + wsg[t] + wtt[t]);
    }

    const int cg = t & 31;   // cols: cg + 32*j
    const int rg = t >> 5;   // rows: rg*4 + i

    float acc[4][4];
    #pragma unroll
    for (int j = 0; j < 4; ++j) {
        float bj = bias[cg + 32 * j];
        #pragma unroll
        for (int i = 0; i < 4; ++i) acc[i][j] = bj;
    }

    const float4* Wsrc = (const float4*)W;
    const float4* Xsrc = (const float4*)X;

    for (int h = 0; h < 2; ++h) {            // K-dim halves (64 each)
        __syncthreads();
        #pragma unroll
        for (int j = 0; j < 8; ++j) {        // W half: 128 rows x 16 f4
            int g = t + j * 256;
            int c = g >> 4, f4 = g & 15;
            float4 v = Wsrc[c * 32 + h * 16 + f4];
            float* dst = &Wl[c * 66 + f4 * 4];
            *(float2*)dst       = make_float2(v.x, v.y);
            *(float2*)(dst + 2) = make_float2(v.z, v.w);
        }
        #pragma unroll
        for (int j = 0; j < 2; ++j) {        // X half: 32 rows x 16 f4
            int g = t + j * 256;
            int r = g >> 4, f4 = g & 15;
            float4 v = Xsrc[(r0 + r) * 32 + h * 16 + f4];
            float* dst = &Xl[r * 66 + f4 * 4];
            *(float2*)dst       = make_float2(v.x, v.y);
            *(float2*)(dst + 2) = make_float2(v.z, v.w);
        }
        __syncthreads();

        #pragma unroll 4
        for (int dg = 0; dg < 32; ++dg) {
            float2 bf[4];
            #pragma unroll
            for (int j = 0; j < 4; ++j)
                bf[j] = *(const float2*)&Wl[(cg + 32 * j) * 66 + 2 * dg];
            float2 af[4];
            #pragma unroll
            for (int i = 0; i < 4; ++i)
                af[i] = *(const float2*)&Xl[(rg * 4 + i) * 66 + 2 * dg];
            #pragma unroll
            for (int i = 0; i < 4; ++i)
                #pragma unroll
                for (int j = 0; j < 4; ++j)
                    acc[i][j] += af[i].x * bf[j].x + af[i].y * bf[j].y;
        }
    }

    if (m == 2) {
        float* oV = ws + (size_t)2 * MATN;  // V
        #pragma unroll
        for (int i = 0; i < 4; ++i) {
            int r = r0 + rg * 4 + i;
            #pragma unroll
            for (int j = 0; j < 4; ++j)
                oV[(size_t)r * DD + cg + 32 * j] = acc[i][j];
        }
    } else {
        float* oE = ws + (size_t)m * MATN;  // Eq (m=0) or Ek (m=1)
        #pragma unroll
        for (int i = 0; i < 4; ++i) {
            int r = r0 + rg * 4 + i;
            #pragma unroll
            for (int j = 0; j < 4; ++j)
                oE[(size_t)r * DD + cg + 32 * j] = fast_exp2(C1 * acc[i][j]);
        }
    }
}

// ---------------------------------------------------------------------------
// Attention main. 1024 blocks x 512 threads (8 waves). Block = 32 q x one
// 64-k tile (k-split 8). Wave = 4 q. Stage Ek->[k][132] once (b128-optimal
// per-lane rows); pass A lane-owns-k, Eq/w^ wave-uniform s_loads; p handed
// to pass B via readlane; V from global (coalesced f2). One barrier pair.
// ---------------------------------------------------------------------------
__global__ __launch_bounds__(512, 4) void attn_kernel(
    const float* __restrict__ ws, float* __restrict__ out,
    float* __restrict__ psumG)
{
    __shared__ __align__(16) float Ekt[64 * 132];   // 33792 B

    const float* Eq  = ws;
    const float* Ek  = ws + (size_t)MATN;
    const float* Vp  = ws + (size_t)2 * MATN;
    const float4* W4 = (const float4*)(ws + (size_t)3 * MATN);

    const int bx   = blockIdx.x;               // 1024 blocks
    const int qblk = bx >> 3;                  // 0..127  (32 q each)
    const int kx   = bx & 7;                   // k-chunk (64 k)
    const int b    = qblk >> 4;                // 16 q-blocks per batch
    const int wave = __builtin_amdgcn_readfirstlane((int)threadIdx.x >> 6);
    const int lane = threadIdx.x & 63;
    const int qa   = qblk * 32 + wave * 4;     // wave-uniform

    {   // stage Ek tile (64 k x 128 d) -> stride-132 rows; 2048 f4 / 512 thr
        const float4* sK = (const float4*)(Ek + (size_t)b * (LL * DD)
                                              + (size_t)kx * 64 * DD);
        #pragma unroll
        for (int r = 0; r < 4; ++r) {
            int g = (int)threadIdx.x + r * 512;    // 0..2047
            int row = g >> 5, c4 = g & 31;
            *(float4*)&Ekt[row * 132 + c4 * 4] = sK[g];
        }
    }
    __syncthreads();

    // ---- pass A: s(qa..qa+3, k=lane) over all 128 d
    const float4* __restrict__ Eq0 = (const float4*)Eq + (size_t)qa * 32;
    const float4* __restrict__ Eq1 = Eq0 + 32;
    const float4* __restrict__ Eq2 = Eq0 + 64;
    const float4* __restrict__ Eq3 = Eq0 + 96;
    const float* krow = &Ekt[lane * 132];

    float s0 = 0.f, s1 = 0.f, s2 = 0.f, s3 = 0.f;
    #pragma unroll 4
    for (int i = 0; i < 32; ++i) {
        float4 w  = W4[i];                          // uniform -> s_load
        float4 kk = *(const float4*)(krow + 4 * i); // per-lane ds_read_b128
        #define QTERM(SS, EQ) { \
            float4 eq = EQ[i]; /* uniform -> s_load */ \
            float e0 = fmaf(eq.x, kk.x, 1.f), e1 = fmaf(eq.y, kk.y, 1.f); \
            float e2 = fmaf(eq.z, kk.z, 1.f), e3 = fmaf(eq.w, kk.w, 1.f); \
            float N01 = fmaf(w.x, e1, w.y * e0); \
            float N23 = fmaf(w.z, e3, w.w * e2); \
            SS = fmaf(N01, fast_rcp(e0 * e1), SS); \
            SS = fmaf(N23, fast_rcp(e2 * e3), SS); }
        QTERM(s0, Eq0) QTERM(s1, Eq1) QTERM(s2, Eq2) QTERM(s3, Eq3)
        #undef QTERM
    }
    float p0 = fast_exp2(s0);     // lane holds p(qa+qq, k = kx*64+lane)
    float p1 = fast_exp2(s1);
    float p2 = fast_exp2(s2);
    float p3 = fast_exp2(s3);

    // psum (sum over this tile's 64 k) -> atomics
    float t0 = p0, t1 = p1, t2 = p2, t3 = p3;
    #pragma unroll
    for (int off = 32; off; off >>= 1) {
        t0 += __shfl_xor(t0, off);
        t1 += __shfl_xor(t1, off);
        t2 += __shfl_xor(t2, off);
        t3 += __shfl_xor(t3, off);
    }
    if (lane == 0) {
        atomicAdd(&psumG[qa + 0], t0);
        atomicAdd(&psumG[qa + 1], t1);
        atomicAdd(&psumG[qa + 2], t2);
        atomicAdd(&psumG[qa + 3], t3);
    }

    // ---- pass B: o += p * V ; lane = d-pair, p via readlane (SGPR)
    const float2* __restrict__ Vg =
        (const float2*)(Vp + (size_t)b * (LL * DD) + (size_t)kx * 64 * DD);
    float2 o[4];
    #pragma unroll
    for (int qq = 0; qq < 4; ++qq) o[qq] = make_float2(0.f, 0.f);

    #pragma unroll 8
    for (int e = 0; e < 64; ++e) {
        float2 v = Vg[(size_t)e * 64 + lane];     // coalesced, L1/L2-shared
        float fa = __shfl(p0, e);                 // uniform idx -> v_readlane
        float fb = __shfl(p1, e);
        float fc = __shfl(p2, e);
        float fd = __shfl(p3, e);
        o[0].x = fmaf(fa, v.x, o[0].x); o[0].y = fmaf(fa, v.y, o[0].y);
        o[1].x = fmaf(fb, v.x, o[1].x); o[1].y = fmaf(fb, v.y, o[1].y);
        o[2].x = fmaf(fc, v.x, o[2].x); o[2].y = fmaf(fc, v.y, o[2].y);
        o[3].x = fmaf(fd, v.x, o[3].x); o[3].y = fmaf(fd, v.y, o[3].y);
    }

    const int d2 = 2 * lane;
    #pragma unroll
    for (int qq = 0; qq < 4; ++qq) {
        atomicAdd(&out[(size_t)(qa + qq) * DD + d2],     o[qq].x);
        atomicAdd(&out[(size_t)(qa + qq) * DD + d2 + 1], o[qq].y);
    }
}

// ---------------------------------------------------------------------------
__global__ __launch_bounds__(256) void norm_kernel(
    float* __restrict__ out, const float* __restrict__ psumG)
{
    int t = blockIdx.x * 256 + threadIdx.x;    // 262144 float2s
    float2* o2 = (float2*)out;
    int q = t >> 6;
    float inv = fast_rcp(psumG[q]);
    float2 v = o2[t];
    o2[t] = make_float2(v.x * inv, v.y * inv);
}

// ---------------------------------------------------------------------------
extern "C" void kernel_launch(void* const* d_in, const int* in_sizes, int n_in,
                              void* d_out, int out_size, void* d_ws, size_t ws_size,
                              hipStream_t stream) {
    const float* query = (const float*)d_in[0];
    const float* key_  = (const float*)d_in[1];
    const float* value = (const float*)d_in[2];
    const float* Wq    = (const float*)d_in[3];
    const float* bq    = (const float*)d_in[4];
    const float* Wk    = (const float*)d_in[5];
    const float* bk    = (const float*)d_in[6];
    const float* Wv    = (const float*)d_in[7];
    const float* bv    = (const float*)d_in[8];
    const float* wd    = (const float*)d_in[9];
    // d_in[10]/[12]/[14] = b_delta/b_sigma/b_theta: softmax-invariant, dropped
    const float* wsg   = (const float*)d_in[11];
    const float* wtt   = (const float*)d_in[13];
    float* ws = (float*)d_ws;   // 3*MATN + 128 + 4096 floats ~ 6.3 MB
    float* psumG = ws + (size_t)3 * MATN + 128;
    float* out = (float*)d_out;

    hipMemsetAsync(out, 0, (size_t)out_size * sizeof(float), stream);
    hipMemsetAsync(psumG, 0, (size_t)NROW * sizeof(float), stream);
    proj_kernel<<<384, 256, 0, stream>>>(query, key_, value,
                                         Wq, bq, Wk, bk, Wv, bv,
                                         wd, wsg, wtt, ws);
    attn_kernel<<<1024, 512, 0, stream>>>(ws, out, psumG);
    norm_kernel<<<1024, 256, 0, stream>>>(out, psumG);
}

// Round 7
// 156.700 us; speedup vs baseline: 1.0305x; 1.0305x over previous
//
#include <hip/hip_runtime.h>

// EfficientAdditiveAttention  B=8, L=512, D=128
//
// combined(q,k) = sum_d w_all[d]*tanh(zq_d + zk_d)  -> softmax_k -> @V
// tanh = 1 - 2/(1+e^{2(zq+zk)});  e^{2(zq+zk)} = Eq*Ek, Eq/Ek precomputed by
// the projection kernel. Softmax-invariant constants dropped. With
// w^ = -2*log2e*w_all:  p(k) = exp2( sum_d w^_d / (1+Eq_d*Ek_d) ).
//
// v7: R6 showed the hot loop stalled on mixed s_load+ds_read lgkm drains
// (VALUBusy 37%). Fix: Eq and w^ staged into LDS as well -> hot loop touches
// ONLY the DS pipe (in-order, fine-grained lgkmcnt). Ek per-lane b128 rows;
// Eq/w^ wave-uniform-address broadcasts (conflict-free). LDS 50.7 KB ->
// 3 blocks/CU. Pass B: p via readlane, V from global. Atomics + norm kernel.

#define BB 8
#define LL 512
#define DD 128
#define NROW (BB*LL)            // 4096 rows
#define MATN (NROW*DD)          // 524288 elements per matrix

static constexpr float C1 = 2.8853900817779268f;    // 2*log2(e)
static constexpr float LOG2E = 1.4426950408889634f;
static constexpr float INV_SCALE = 0.08838834764831845f; // 1/sqrt(128)

__device__ __forceinline__ float fast_exp2(float x) { return __builtin_amdgcn_exp2f(x); }
__device__ __forceinline__ float fast_rcp(float x)  { return __builtin_amdgcn_rcpf(x); }

// ---------------------------------------------------------------------------
// Projection: z = X @ W.T + b; outputs Eq=exp2(C1*z) (m=0), Ek=exp2(C1*z)
// (m=1), V=z (m=2). 32-row x 128-col tiles, 384 blocks x 256 threads.
// ---------------------------------------------------------------------------
__global__ __launch_bounds__(256) void proj_kernel(
    const float* __restrict__ query, const float* __restrict__ key,
    const float* __restrict__ value,
    const float* __restrict__ Wq, const float* __restrict__ bq,
    const float* __restrict__ Wk, const float* __restrict__ bk,
    const float* __restrict__ Wv, const float* __restrict__ bv,
    const float* __restrict__ wd, const float* __restrict__ wsg,
    const float* __restrict__ wtt, float* __restrict__ ws)
{
    __shared__ __align__(16) float Wl[128 * 66];   // 33792 B
    __shared__ __align__(16) float Xl[32 * 66];    //  8448 B

    const int bx = blockIdx.x;
    const int m  = bx >> 7;              // 0:Q 1:K 2:V  (128 row-tiles each)
    const int r0 = (bx & 127) * 32;
    const float* X    = (m == 0) ? query : (m == 1) ? key : value;
    const float* W    = (m == 0) ? Wq    : (m == 1) ? Wk  : Wv;
    const float* bias = (m == 0) ? bq    : (m == 1) ? bk  : bv;
    const int t = threadIdx.x;

    // w^ = -2*log2e*(1/sqrt(D) + wd + wsg + wtt)  -> ws tail (block 0)
    if (bx == 0 && t < 128) {
        ws[(size_t)3 * MATN + t] =
            -2.0f * LOG2E * (INV_SCALE + wd[t] + wsg[t] + wtt[t]);
    }

    const int cg = t & 31;   // cols: cg + 32*j
    const int rg = t >> 5;   // rows: rg*4 + i

    float acc[4][4];
    #pragma unroll
    for (int j = 0; j < 4; ++j) {
        float bj = bias[cg + 32 * j];
        #pragma unroll
        for (int i = 0; i < 4; ++i) acc[i][j] = bj;
    }

    const float4* Wsrc = (const float4*)W;
    const float4* Xsrc = (const float4*)X;

    for (int h = 0; h < 2; ++h) {            // K-dim halves (64 each)
        __syncthreads();
        #pragma unroll
        for (int j = 0; j < 8; ++j) {        // W half: 128 rows x 16 f4
            int g = t + j * 256;
            int c = g >> 4, f4 = g & 15;
            float4 v = Wsrc[c * 32 + h * 16 + f4];
            float* dst = &Wl[c * 66 + f4 * 4];
            *(float2*)dst       = make_float2(v.x, v.y);
            *(float2*)(dst + 2) = make_float2(v.z, v.w);
        }
        #pragma unroll
        for (int j = 0; j < 2; ++j) {        // X half: 32 rows x 16 f4
            int g = t + j * 256;
            int r = g >> 4, f4 = g & 15;
            float4 v = Xsrc[(r0 + r) * 32 + h * 16 + f4];
            float* dst = &Xl[r * 66 + f4 * 4];
            *(float2*)dst       = make_float2(v.x, v.y);
            *(float2*)(dst + 2) = make_float2(v.z, v.w);
        }
        __syncthreads();

        #pragma unroll 4
        for (int dg = 0; dg < 32; ++dg) {
            float2 bf[4];
            #pragma unroll
            for (int j = 0; j < 4; ++j)
                bf[j] = *(const float2*)&Wl[(cg + 32 * j) * 66 + 2 * dg];
            float2 af[4];
            #pragma unroll
            for (int i = 0; i < 4; ++i)
                af[i] = *(const float2*)&Xl[(rg * 4 + i) * 66 + 2 * dg];
            #pragma unroll
            for (int i = 0; i < 4; ++i)
                #pragma unroll
                for (int j = 0; j < 4; ++j)
                    acc[i][j] += af[i].x * bf[j].x + af[i].y * bf[j].y;
        }
    }

    if (m == 2) {
        float* oV = ws + (size_t)2 * MATN;  // V
        #pragma unroll
        for (int i = 0; i < 4; ++i) {
            int r = r0 + rg * 4 + i;
            #pragma unroll
            for (int j = 0; j < 4; ++j)
                oV[(size_t)r * DD + cg + 32 * j] = acc[i][j];
        }
    } else {
        float* oE = ws + (size_t)m * MATN;  // Eq (m=0) or Ek (m=1)
        #pragma unroll
        for (int i = 0; i < 4; ++i) {
            int r = r0 + rg * 4 + i;
            #pragma unroll
            for (int j = 0; j < 4; ++j)
                oE[(size_t)r * DD + cg + 32 * j] = fast_exp2(C1 * acc[i][j]);
        }
    }
}

// ---------------------------------------------------------------------------
// Attention main. 1024 blocks x 512 threads (8 waves). Block = 32 q x one
// 64-k tile (k-split 8). Wave = 4 q. Stage Ek->[k][132] (per-lane b128 rows),
// Eq->[32][128] and w^ -> LDS (broadcast reads). Hot loop is DS-pipe only.
// p handed to pass B via readlane; V from global. Partials -> f32 atomics.
// ---------------------------------------------------------------------------
__global__ __launch_bounds__(512) void attn_kernel(
    const float* __restrict__ ws, float* __restrict__ out,
    float* __restrict__ psumG)
{
    __shared__ __align__(16) float Ekt[64 * 132];   // 33792 B
    __shared__ __align__(16) float Eqt[32 * 128];   // 16384 B
    __shared__ __align__(16) float wt[128];         //   512 B  -> 50688 total

    const float* Eq  = ws;
    const float* Ek  = ws + (size_t)MATN;
    const float* Vp  = ws + (size_t)2 * MATN;

    const int bx   = blockIdx.x;               // 1024 blocks
    const int qblk = bx >> 3;                  // 0..127  (32 q each)
    const int kx   = bx & 7;                   // k-chunk (64 k)
    const int b    = qblk >> 4;                // 16 q-blocks per batch
    const int wave = __builtin_amdgcn_readfirstlane((int)threadIdx.x >> 6);
    const int lane = threadIdx.x & 63;
    const int qa   = qblk * 32 + wave * 4;     // wave-uniform (global q base)

    {   // stage Ek tile (64 k x 128 d) -> stride-132 rows
        const float4* sK = (const float4*)(Ek + (size_t)b * (LL * DD)
                                              + (size_t)kx * 64 * DD);
        #pragma unroll
        for (int r = 0; r < 4; ++r) {
            int g = (int)threadIdx.x + r * 512;    // 0..2047
            int row = g >> 5, c4 = g & 31;
            *(float4*)&Ekt[row * 132 + c4 * 4] = sK[g];
        }
        // stage Eq block (32 q x 128 d), linear
        const float4* sQ = (const float4*)(Eq + (size_t)qblk * 32 * DD);
        #pragma unroll
        for (int r = 0; r < 2; ++r) {
            int g = (int)threadIdx.x + r * 512;    // 0..1023
            ((float4*)Eqt)[g] = sQ[g];
        }
        // stage w^
        if (threadIdx.x < 32)
            ((float4*)wt)[threadIdx.x] =
                ((const float4*)(ws + (size_t)3 * MATN))[threadIdx.x];
    }
    __syncthreads();

    // ---- pass A: s(qa..qa+3, k = kx*64+lane) over all 128 d, DS-only loop
    const float*  krow = &Ekt[lane * 132];               // per-lane row
    const float4* eq4  = (const float4*)&Eqt[(wave * 4) * 128]; // bcast base
    const float4* w4l  = (const float4*)wt;

    float s0 = 0.f, s1 = 0.f, s2 = 0.f, s3 = 0.f;
    #pragma unroll 4
    for (int i = 0; i < 32; ++i) {
        float4 w  = w4l[i];                          // ds broadcast
        float4 kk = *(const float4*)(krow + 4 * i);  // per-lane ds_read_b128
        #define QTERM(SS, QQ) { \
            float4 eq = eq4[QQ * 32 + i]; /* ds broadcast */ \
            float e0 = fmaf(eq.x, kk.x, 1.f), e1 = fmaf(eq.y, kk.y, 1.f); \
            float e2 = fmaf(eq.z, kk.z, 1.f), e3 = fmaf(eq.w, kk.w, 1.f); \
            float N01 = fmaf(w.x, e1, w.y * e0); \
            float N23 = fmaf(w.z, e3, w.w * e2); \
            SS = fmaf(N01, fast_rcp(e0 * e1), SS); \
            SS = fmaf(N23, fast_rcp(e2 * e3), SS); }
        QTERM(s0, 0) QTERM(s1, 1) QTERM(s2, 2) QTERM(s3, 3)
        #undef QTERM
    }
    float p0 = fast_exp2(s0);     // lane holds p(qa+qq, k = kx*64+lane)
    float p1 = fast_exp2(s1);
    float p2 = fast_exp2(s2);
    float p3 = fast_exp2(s3);

    // psum (sum over this tile's 64 k) -> atomics
    float t0 = p0, t1 = p1, t2 = p2, t3 = p3;
    #pragma unroll
    for (int off = 32; off; off >>= 1) {
        t0 += __shfl_xor(t0, off);
        t1 += __shfl_xor(t1, off);
        t2 += __shfl_xor(t2, off);
        t3 += __shfl_xor(t3, off);
    }
    if (lane == 0) {
        atomicAdd(&psumG[qa + 0], t0);
        atomicAdd(&psumG[qa + 1], t1);
        atomicAdd(&psumG[qa + 2], t2);
        atomicAdd(&psumG[qa + 3], t3);
    }

    // ---- pass B: o += p * V ; lane = d-pair, p via readlane (SGPR)
    const float2* __restrict__ Vg =
        (const float2*)(Vp + (size_t)b * (LL * DD) + (size_t)kx * 64 * DD);
    float2 o[4];
    #pragma unroll
    for (int qq = 0; qq < 4; ++qq) o[qq] = make_float2(0.f, 0.f);

    #pragma unroll 8
    for (int e = 0; e < 64; ++e) {
        float2 v = Vg[(size_t)e * 64 + lane];     // coalesced, L1/L2-shared
        float fa = __shfl(p0, e);                 // uniform idx -> v_readlane
        float fb = __shfl(p1, e);
        float fc = __shfl(p2, e);
        float fd = __shfl(p3, e);
        o[0].x = fmaf(fa, v.x, o[0].x); o[0].y = fmaf(fa, v.y, o[0].y);
        o[1].x = fmaf(fb, v.x, o[1].x); o[1].y = fmaf(fb, v.y, o[1].y);
        o[2].x = fmaf(fc, v.x, o[2].x); o[2].y = fmaf(fc, v.y, o[2].y);
        o[3].x = fmaf(fd, v.x, o[3].x); o[3].y = fmaf(fd, v.y, o[3].y);
    }

    const int d2 = 2 * lane;
    #pragma unroll
    for (int qq = 0; qq < 4; ++qq) {
        atomicAdd(&out[(size_t)(qa + qq) * DD + d2],     o[qq].x);
        atomicAdd(&out[(size_t)(qa + qq) * DD + d2 + 1], o[qq].y);
    }
}

// ---------------------------------------------------------------------------
__global__ __launch_bounds__(256) void norm_kernel(
    float* __restrict__ out, const float* __restrict__ psumG)
{
    int t = blockIdx.x * 256 + threadIdx.x;    // 262144 float2s
    float2* o2 = (float2*)out;
    int q = t >> 6;
    float inv = fast_rcp(psumG[q]);
    float2 v = o2[t];
    o2[t] = make_float2(v.x * inv, v.y * inv);
}

// ---------------------------------------------------------------------------
extern "C" void kernel_launch(void* const* d_in, const int* in_sizes, int n_in,
                              void* d_out, int out_size, void* d_ws, size_t ws_size,
                              hipStream_t stream) {
    const float* query = (const float*)d_in[0];
    const float* key_  = (const float*)d_in[1];
    const float* value = (const float*)d_in[2];
    const float* Wq    = (const float*)d_in[3];
    const float* bq    = (const float*)d_in[4];
    const float* Wk    = (const float*)d_in[5];
    const float* bk    = (const float*)d_in[6];
    const float* Wv    = (const float*)d_in[7];
    const float* bv    = (const float*)d_in[8];
    const float* wd    = (const float*)d_in[9];
    // d_in[10]/[12]/[14] = b_delta/b_sigma/b_theta: softmax-invariant, dropped
    const float* wsg   = (const float*)d_in[11];
    const float* wtt   = (const float*)d_in[13];
    float* ws = (float*)d_ws;   // 3*MATN + 128 + 4096 floats ~ 6.3 MB
    float* psumG = ws + (size_t)3 * MATN + 128;
    float* out = (float*)d_out;

    hipMemsetAsync(out, 0, (size_t)out_size * sizeof(float), stream);
    hipMemsetAsync(psumG, 0, (size_t)NROW * sizeof(float), stream);
    proj_kernel<<<384, 256, 0, stream>>>(query, key_, value,
                                         Wq, bq, Wk, bk, Wv, bv,
                                         wd, wsg, wtt, ws);
    attn_kernel<<<1024, 512, 0, stream>>>(ws, out, psumG);
    norm_kernel<<<1024, 256, 0, stream>>>(out, psumG);
}